// Round 6
// baseline (1105.671 us; speedup 1.0000x reference)
//
#include <hip/hip_runtime.h>

// VQ layer: N=262144 rows (D=256), K=1024 codes.
// out (FLOAT32): [z_q: N*D][loss_vq][loss_mean][indices(as float): N]
//
// Indices must match numpy-f32 argmin of
//   d = fl32( fl32(A_np + s_np,k) - fl32(2 * M_k) ),  tie -> lowest index,
// where A_np/s_np are numpy pairwise f32 sums and M_k is the BLAS sgemm f32
// serial-FMA-chain dot (K=256, ascending k). fp16-MFMA pass decides rows with
// top-2 gap >= 5e-4; flagged rows are np-emulated exactly (pair or full scan).

#define NROWS 262144
#define KCODES 1024
#define DDIM 256
#define ND ((size_t)NROWS * (size_t)DDIM)
#define M1 5e-4f

typedef unsigned int uint;
typedef _Float16 f16x8 __attribute__((ext_vector_type(8)));
typedef _Float16 f16x4 __attribute__((ext_vector_type(4)));
typedef float f32x4v __attribute__((ext_vector_type(4)));

// ---- IEEE-exact f32 ops, immune to contraction/reassociation ----
__device__ inline float fadd(float a, float b) {
    float d; asm volatile("v_add_f32 %0, %1, %2" : "=v"(d) : "v"(a), "v"(b)); return d;
}
__device__ inline float fmul(float a, float b) {
    float d; asm volatile("v_mul_f32 %0, %1, %2" : "=v"(d) : "v"(a), "v"(b)); return d;
}
__device__ inline float fsub(float a, float b) {
    float d; asm volatile("v_sub_f32 %0, %1, %2" : "=v"(d) : "v"(a), "v"(b)); return d;
}
__device__ inline float ffma(float a, float b, float c) {
    float d; asm volatile("v_fma_f32 %0, %1, %2, %3" : "=v"(d) : "v"(a), "v"(b), "v"(c)); return d;
}

// numpy pairwise sum of a[i]^2, n=256: pw(a,128)+pw(a+128,128); each 128-block:
// 8 strided accumulators, combined ((r0+r1)+(r2+r3))+((r4+r5)+(r6+r7)).
__device__ float np_sq_sum256(const float* __restrict__ a) {
    float tot[2];
    #pragma unroll 1
    for (int h = 0; h < 2; ++h) {
        const float* p = a + h * 128;
        float r[8];
        #pragma unroll
        for (int j = 0; j < 8; ++j) r[j] = fmul(p[j], p[j]);
        #pragma unroll 1
        for (int i = 8; i < 128; i += 8)
            #pragma unroll
            for (int j = 0; j < 8; ++j) r[j] = fadd(r[j], fmul(p[i + j], p[i + j]));
        tot[h] = fadd(fadd(fadd(r[0], r[1]), fadd(r[2], r[3])),
                      fadd(fadd(r[4], r[5]), fadd(r[6], r[7])));
    }
    return fadd(tot[0], tot[1]);
}

// BLAS-style f32 dot: single-accumulator serial FMA chain, ascending k.
__device__ float blas_dot256(const float* __restrict__ zr, const float* __restrict__ cr) {
    float dot = 0.f;
    #pragma unroll 1
    for (int d4 = 0; d4 < 64; ++d4) {
        float4 zz = *(const float4*)(zr + d4 * 4);
        float4 cc = *(const float4*)(cr + d4 * 4);
        dot = ffma(zz.x, cc.x, dot); dot = ffma(zz.y, cc.y, dot);
        dot = ffma(zz.z, cc.z, dot); dot = ffma(zz.w, cc.w, dot);
    }
    return dot;
}

// ---- k1a: per-code numpy-pairwise squared norms (f32) ----
__global__ void k_codestats(const float* __restrict__ cb, float* __restrict__ scp) {
    int code = blockIdx.x * blockDim.x + threadIdx.x;
    if (code < KCODES) scp[code] = np_sq_sum256(cb + (size_t)code * DDIM);
}

// ---- k1b: codebook column sums (for loss_mean) ----
__global__ void k_colsum(const float* __restrict__ cb, float* __restrict__ mAcc) {
    int d = threadIdx.x;
    int b = blockIdx.x; // 16 blocks x 64 rows
    float s = 0.f;
    for (int i = 0; i < 64; ++i) s += cb[(size_t)(b * 64 + i) * DDIM + d];
    atomicAdd(&mAcc[d], s);
}

// ---- k1c: finalize mean vector + ||m||^2 ----
__global__ void k_meanfin(const float* __restrict__ mAcc,
                          float* __restrict__ mvec, double* __restrict__ M2p) {
    __shared__ double red[256];
    int d = threadIdx.x;
    float m = mAcc[d] * (1.0f / 1024.0f);
    mvec[d] = m;
    red[d] = (double)m * (double)m;
    __syncthreads();
    for (int off = 128; off; off >>= 1) {
        if (d < off) red[d] += red[d + off];
        __syncthreads();
    }
    if (d == 0) *M2p = red[0];
}

// ---- k2: main fp16-MFMA distance pass; top-3 -> encoded f32 index slot ----
// enc = i1 | i2<<10 | flag<<20; flag: 0 done, 1 pair-emulate, 2 full-emulate.
__launch_bounds__(256, 2)
__global__ void k_main(const float* __restrict__ z, const float* __restrict__ cb,
                       const float* __restrict__ sc, const float* __restrict__ mvec,
                       float* __restrict__ out,
                       double* __restrict__ lossA, double* __restrict__ lossB) {
    __shared__ _Float16 cb_lds[64 * 256];   // 32 KB, XOR-swizzled
    __shared__ float sc_lds[1024];
    __shared__ float statA[128], statZM[128];
    __shared__ float lred[2];

    const int tid = threadIdx.x;
    const int wave = tid >> 6;
    const int lane = tid & 63;
    const int l15 = lane & 15;
    const int lg = lane >> 4;           // 0..3
    const int blockRow = blockIdx.x * 128;

    if (tid < 2) lred[tid] = 0.f;
    for (int i = tid; i < 1024; i += 256) sc_lds[i] = sc[i];

    // --- load z rows -> fp16 A-frags; per-row sum(z^2), z.m (loss only) ---
    f16x8 za[2][8];
    #pragma unroll
    for (int m = 0; m < 2; ++m) {
        const float* zr = z + (size_t)(blockRow + wave * 32 + m * 16 + l15) * DDIM;
        float a2 = 0.f, zm = 0.f;
        #pragma unroll
        for (int kk = 0; kk < 8; ++kk) {
            int d0 = kk * 32 + lg * 8;
            float4 v0 = *(const float4*)(zr + d0);
            float4 v1 = *(const float4*)(zr + d0 + 4);
            float4 w0 = *(const float4*)(mvec + d0);
            float4 w1 = *(const float4*)(mvec + d0 + 4);
            a2 += v0.x * v0.x + v0.y * v0.y + v0.z * v0.z + v0.w * v0.w;
            a2 += v1.x * v1.x + v1.y * v1.y + v1.z * v1.z + v1.w * v1.w;
            zm += v0.x * w0.x + v0.y * w0.y + v0.z * w0.z + v0.w * w0.w;
            zm += v1.x * w1.x + v1.y * w1.y + v1.z * w1.z + v1.w * w1.w;
            f16x8 h;
            h[0] = (_Float16)v0.x; h[1] = (_Float16)v0.y;
            h[2] = (_Float16)v0.z; h[3] = (_Float16)v0.w;
            h[4] = (_Float16)v1.x; h[5] = (_Float16)v1.y;
            h[6] = (_Float16)v1.z; h[7] = (_Float16)v1.w;
            za[m][kk] = h;
        }
        a2 += __shfl_xor(a2, 16); a2 += __shfl_xor(a2, 32);
        zm += __shfl_xor(zm, 16); zm += __shfl_xor(zm, 32);
        if (lg == 0) {
            statA[wave * 32 + m * 16 + l15] = a2;
            statZM[wave * 32 + m * 16 + l15] = zm;
        }
    }
    __syncthreads();

    float m1v[2][4], m2v[2][4], m3v[2][4];
    int i1v[2][4], i2v[2][4];
    #pragma unroll
    for (int m = 0; m < 2; ++m)
        #pragma unroll
        for (int r = 0; r < 4; ++r) {
            m1v[m][r] = 1e30f; m2v[m][r] = 1e30f; m3v[m][r] = 1e30f;
            i1v[m][r] = 0; i2v[m][r] = 0;
        }

    #pragma unroll 1
    for (int t = 0; t < 16; ++t) {
        const float4* src = (const float4*)(cb + (size_t)t * 64 * DDIM);
        #pragma unroll
        for (int i = 0; i < 16; ++i) {
            int f = i * 256 + tid;          // 0..4095
            int code = f >> 6, d4 = f & 63;
            float4 v = src[f];
            f16x4 h;
            h[0] = (_Float16)(v.x * 1024.f); h[1] = (_Float16)(v.y * 1024.f);
            h[2] = (_Float16)(v.z * 1024.f); h[3] = (_Float16)(v.w * 1024.f);
            uint byte = (uint)(code * 512 + d4 * 8) ^ (uint)((code & 7) << 4);
            *(f16x4*)((char*)cb_lds + byte) = h;
        }
        __syncthreads();

        f32x4v acc[2][4];
        #pragma unroll
        for (int m = 0; m < 2; ++m)
            #pragma unroll
            for (int n = 0; n < 4; ++n) acc[m][n] = (f32x4v){0.f, 0.f, 0.f, 0.f};

        #pragma unroll
        for (int kk = 0; kk < 8; ++kk) {
            f16x8 b[4];
            #pragma unroll
            for (int n = 0; n < 4; ++n) {
                int code = n * 16 + l15;
                uint byte = (uint)(code * 512 + kk * 64 + lg * 16) ^ (uint)((code & 7) << 4);
                b[n] = *(const f16x8*)((const char*)cb_lds + byte);
            }
            #pragma unroll
            for (int n = 0; n < 4; ++n)
                #pragma unroll
                for (int m = 0; m < 2; ++m)
                    acc[m][n] = __builtin_amdgcn_mfma_f32_16x16x32_f16(
                        za[m][kk], b[n], acc[m][n], 0, 0, 0);
        }
        __syncthreads();

        #pragma unroll
        for (int n = 0; n < 4; ++n) {
            int code = t * 64 + n * 16 + l15;
            float scv = sc_lds[code];
            #pragma unroll
            for (int m = 0; m < 2; ++m)
                #pragma unroll
                for (int r = 0; r < 4; ++r) {
                    float s = fmaf(acc[m][n][r], -0.001953125f, scv);
                    if (s < m1v[m][r]) {
                        m3v[m][r] = m2v[m][r]; m2v[m][r] = m1v[m][r];
                        i2v[m][r] = i1v[m][r];
                        m1v[m][r] = s; i1v[m][r] = code;
                    } else if (s < m2v[m][r]) {
                        m3v[m][r] = m2v[m][r]; m2v[m][r] = s; i2v[m][r] = code;
                    } else if (s < m3v[m][r]) {
                        m3v[m][r] = s;
                    }
                }
        }
    }

    float lA = 0.f, lB = 0.f;
    #pragma unroll
    for (int m = 0; m < 2; ++m)
        #pragma unroll
        for (int r = 0; r < 4; ++r) {
            float a1 = m1v[m][r], a2 = m2v[m][r], a3 = m3v[m][r];
            int ai1 = i1v[m][r], ai2 = i2v[m][r];
            #pragma unroll
            for (int mk = 1; mk <= 8; mk <<= 1) {
                float b1 = __shfl_xor(a1, mk);
                float b2 = __shfl_xor(a2, mk);
                float b3 = __shfl_xor(a3, mk);
                int bi1 = __shfl_xor(ai1, mk);
                int bi2 = __shfl_xor(ai2, mk);
                if (b1 < a1) {
                    if (a1 < b2) { a3 = fminf(a2, b2); a2 = a1; ai2 = ai1; }
                    else         { a3 = fminf(a1, b3); a2 = b2; ai2 = bi2; }
                    a1 = b1; ai1 = bi1;
                } else {
                    if (b1 < a2) { a3 = fminf(a2, b2); a2 = b1; ai2 = bi1; }
                    else         { a3 = fminf(b1, a3); }
                }
            }
            if (l15 == 0) {
                int rowL = wave * 32 + m * 16 + lg * 4 + r;
                int row = blockRow + rowL;
                int flag = (a3 - a1 < M1) ? 2 : ((a2 - a1 < M1) ? 1 : 0);
                int enc = (flag == 0) ? ai1
                        : ((ai1 & 1023) | ((ai2 & 1023) << 10) | (flag << 20));
                out[ND + 2 + (size_t)row] = (float)enc;   // exact (< 2^24)
                lA += statA[rowL] + a1;
                lB += statA[rowL] - 2.f * statZM[rowL];
            }
        }
    if (l15 == 0) { atomicAdd(&lred[0], lA); atomicAdd(&lred[1], lB); }
    __syncthreads();
    if (tid == 0) {
        atomicAdd(lossA, (double)lred[0]);
        atomicAdd(lossB, (double)lred[1]);
    }
}

// ---- k3: np-f32-emulated resolution of flagged rows ----
__launch_bounds__(256, 2)
__global__ void k_refine(const float* __restrict__ z, const float* __restrict__ cb,
                         const float* __restrict__ scp, float* __restrict__ out) {
    __shared__ float zrow[256];
    __shared__ float Arow;
    __shared__ float dsc[2];
    __shared__ float av[256];
    __shared__ int ai[256];

    const int tid = threadIdx.x;
    const int base = blockIdx.x * 32;

    #pragma unroll 1
    for (int k = 0; k < 32; ++k) {
        int row = base + k;
        int w = (int)out[ND + 2 + (size_t)row];
        int flag = (w >> 20) & 3;
        if (flag == 0) continue;          // uniform across block
        __syncthreads();                  // protect zrow/av reuse
        if (tid < 64)
            *(float4*)&zrow[tid * 4] = *(const float4*)(z + (size_t)row * DDIM + tid * 4);
        __syncthreads();
        if (tid == 0) Arow = np_sq_sum256(zrow);

        int i1 = w & 1023, i2 = (w >> 10) & 1023;

        if (flag == 1) {
            // pair: two BLAS-chain dots
            if (tid < 2) {
                int code = (tid == 0) ? i1 : i2;
                dsc[tid] = blas_dot256(zrow, cb + (size_t)code * DDIM);
            }
            __syncthreads();
            if (tid == 0) {
                float A = Arow;
                float d1 = fsub(fadd(A, scp[i1]), 2.0f * dsc[0]);
                float d2 = fsub(fadd(A, scp[i2]), 2.0f * dsc[1]);
                int win = (d2 < d1 || (d2 == d1 && i2 < i1)) ? i2 : i1;
                out[ND + 2 + (size_t)row] = (float)win;
            }
            __syncthreads();
        } else {
            // full scan: thread t emulates codes t, t+256, t+512, t+768
            __syncthreads();              // Arow visible
            float A = Arow;
            float best = 1e30f; int bi = 0x7fffffff;
            #pragma unroll
            for (int kk = 0; kk < 4; ++kk) {
                int code = tid + kk * 256;
                float dot = blas_dot256(zrow, cb + (size_t)code * DDIM);
                float d = fsub(fadd(A, scp[code]), 2.0f * dot);
                if (d < best || (d == best && code < bi)) { best = d; bi = code; }
            }
            av[tid] = best; ai[tid] = bi;
            __syncthreads();
            for (int off = 128; off; off >>= 1) {
                if (tid < off) {
                    float o = av[tid + off]; int oi = ai[tid + off];
                    if (o < av[tid] || (o == av[tid] && oi < ai[tid])) {
                        av[tid] = o; ai[tid] = oi;
                    }
                }
                __syncthreads();
            }
            if (tid == 0) out[ND + 2 + (size_t)row] = (float)ai[0];
            __syncthreads();
        }
    }
}

// ---- k4: finalize scalar losses ----
__global__ void k_final(const double* __restrict__ lossA, const double* __restrict__ lossB,
                        const double* __restrict__ M2p, float* __restrict__ out) {
    if (threadIdx.x == 0) {
        double nd = (double)ND;
        out[ND] = (float)(*lossA / nd);
        out[ND + 1] = (float)((*lossB + (double)NROWS * (*M2p)) / nd);
    }
}

// ---- k5 (LAST): gather z_q (f32) from final float indices ----
__global__ void k_gather(const float* __restrict__ cb, float* __restrict__ out) {
    const int tid = threadIdx.x;
    const int blockRow = blockIdx.x * 128;
    float4* out4 = (float4*)out;
    const float4* cb4 = (const float4*)cb;
    #pragma unroll 1
    for (int i = 0; i < 32; ++i) {
        int q = i * 256 + tid;              // 128 rows x 64 float4
        int rowL = q >> 6, ch = q & 63;
        int row = blockRow + rowL;
        int code = (int)out[ND + 2 + (size_t)row] & 1023;
        out4[(size_t)row * 64 + ch] = cb4[(size_t)code * 64 + ch];
    }
}

extern "C" void kernel_launch(void* const* d_in, const int* in_sizes, int n_in,
                              void* d_out, int out_size, void* d_ws, size_t ws_size,
                              hipStream_t stream) {
    const float* z = (const float*)d_in[0];
    const float* cb = (const float*)d_in[1];
    float* out = (float*)d_out;

    // ws layout (8 KB)
    double* lossA = (double*)d_ws;                       // 0
    double* lossB = lossA + 1;                           // 8
    double* M2p   = lossA + 2;                           // 16
    float*  mAcc  = (float*)((char*)d_ws + 32);          // 32..1056 (zeroed)
    float*  mvec  = (float*)((char*)d_ws + 2048);        // 256 f
    float*  scp   = (float*)((char*)d_ws + 4096);        // 1024 f (np-pairwise)

    hipMemsetAsync(d_ws, 0, 1056, stream);
    k_codestats<<<4, 256, 0, stream>>>(cb, scp);
    k_colsum<<<16, 256, 0, stream>>>(cb, mAcc);
    k_meanfin<<<1, 256, 0, stream>>>(mAcc, mvec, M2p);
    k_main<<<NROWS / 128, 256, 0, stream>>>(z, cb, scp, mvec, out, lossA, lossB);
    k_refine<<<NROWS / 32, 256, 0, stream>>>(z, cb, scp, out);
    k_final<<<1, 64, 0, stream>>>(lossA, lossB, M2p, out);
    k_gather<<<NROWS / 128, 256, 0, stream>>>(cb, out);
}